// Round 4
// baseline (364.567 us; speedup 1.0000x reference)
//
#include <hip/hip_runtime.h>
#include <math.h>

// Problem: peak_map [256, 131072] f32, scalar logit_thresh.
// Outputs concatenated: smooth_peaks [256*131072] f32, peak_mask [256*131072] f32 (0/1).
#define ROWS 256
#define COLS 131072
#define SHARP 10.0f

typedef float vf4 __attribute__((ext_vector_type(4)));

// Structure = round-2 (twice-verified): each WAVE owns 1024 contiguous elements
// of one row; lane l, chunk c handles [wbase + c*256 + 4l, +4). Every vector
// load/store is 64 lanes x 16B = 1KB contiguous (full lines; nt stores can't
// amplify — round-1 lesson).
//
// Round-4 change (ONLY data movement, all values bitwise-identical to round 2):
// interior halo elements come from __shfl_up/__shfl_down of the already-loaded
// a[c] registers instead of 16 per-thread scalar re-loads of resident lines.
// Only lane 0 / lane 63 load halos from memory, at the SAME clamped addresses
// round 2 used for those lanes. Math (expf + IEEE div, per-window fmax chain)
// is untouched: the s >= thresh mask boundary is a correctness cliff (compare
// threshold 0.02; one flip = 1.0), so no fast-math.
__global__ __launch_bounds__(256) void peak_extract_kernel(
    const float* __restrict__ x,
    const float* __restrict__ logit_thresh,
    float* __restrict__ smooth,
    float* __restrict__ mask)
{
    const float thresh = 1.0f / (1.0f + expf(-logit_thresh[0]));

    const long long gid = (long long)blockIdx.x * blockDim.x + threadIdx.x;
    const int wave = (int)(gid >> 6);
    const int lane = (int)(gid & 63);
    const long long wbase = (long long)wave << 10;   // 1024 elements per wave
    const int row  = (int)(wbase >> 17);             // COLS = 2^17
    const int col0 = (((int)wbase) & (COLS - 1)) + (lane << 2);

    const float* __restrict__ xr = x + (long long)row * COLS;

    // All 4 primary loads issued upfront (4 independent lines in flight/thread).
    vf4 a[4];
#pragma unroll
    for (int c = 0; c < 4; ++c)
        a[c] = *(const vf4*)(xr + col0 + (c << 8));

    const long long rbase = (long long)row * COLS;

#pragma unroll
    for (int c = 0; c < 4; ++c) {
        const int col = col0 + (c << 8);

        // Interior halos: neighbor lanes already hold them in registers.
        // v[0]=x[col-2]=lane(l-1).a[c][2], v[1]=x[col-1]=lane(l-1).a[c][3]
        // v[6]=x[col+4]=lane(l+1).a[c][0], v[7]=x[col+5]=lane(l+1).a[c][1]
        float hl0 = __shfl_up(a[c][2], 1);
        float hl1 = __shfl_up(a[c][3], 1);
        float hr0 = __shfl_down(a[c][0], 1);
        float hr1 = __shfl_down(a[c][1], 1);
        // Wave-boundary lanes: same clamped scalar loads round 2 issued for
        // these lanes (exec-masked to 1 lane each => 64x less halo TA work).
        if (lane == 0) {
            hl0 = xr[max(col - 2, 0)];
            hl1 = xr[max(col - 1, 0)];
        }
        if (lane == 63) {
            hr0 = xr[min(col + 4, COLS - 1)];
            hr1 = xr[min(col + 5, COLS - 1)];
        }

        float v[8];
        v[0] = hl0; v[1] = hl1;
        v[2] = a[c][0]; v[3] = a[c][1]; v[4] = a[c][2]; v[5] = a[c][3];
        v[6] = hr0; v[7] = hr1;

        vf4 sv, mv;
#pragma unroll
        for (int k = 0; k < 4; ++k) {
            // pooled = max over window of 5 centered at element k (v[k..k+4]) —
            // same chain shape as the passing round-0/round-2 kernels.
            float p = v[k];
            p = fmaxf(p, v[k + 1]);
            p = fmaxf(p, v[k + 2]);
            p = fmaxf(p, v[k + 3]);
            p = fmaxf(p, v[k + 4]);
            const float xv   = v[k + 2];
            const float gate = 1.0f / (1.0f + expf(-SHARP * (xv - thresh)));
            const float lm   = 1.0f / (1.0f + expf(-SHARP * (xv - p)));
            const float s    = xv * gate * lm;
            sv[k] = s;
            mv[k] = (s >= thresh) ? 1.0f : 0.0f;
        }
        __builtin_nontemporal_store(sv, (vf4*)(smooth + rbase + col));
        __builtin_nontemporal_store(mv, (vf4*)(mask   + rbase + col));
    }
}

extern "C" void kernel_launch(void* const* d_in, const int* in_sizes, int n_in,
                              void* d_out, int out_size, void* d_ws, size_t ws_size,
                              hipStream_t stream) {
    const float* x            = (const float*)d_in[0];
    const float* logit_thresh = (const float*)d_in[1];

    float* smooth = (float*)d_out;                          // first output, ROWS*COLS f32
    float* mask   = (float*)d_out + (long long)ROWS * COLS; // second output, ROWS*COLS f32

    const long long n_elem   = (long long)ROWS * COLS;      // 33,554,432
    const long long n_thread = n_elem / 16;                 // 2,097,152
    const int block = 256;
    const int grid  = (int)(n_thread / block);              // 8,192

    peak_extract_kernel<<<grid, block, 0, stream>>>(x, logit_thresh, smooth, mask);
}

// Round 5
// 350.331 us; speedup vs baseline: 1.0406x; 1.0406x over previous
//
#include <hip/hip_runtime.h>
#include <math.h>

// Problem: peak_map [256, 131072] f32, scalar logit_thresh.
// Outputs concatenated: smooth_peaks [256*131072] f32, peak_mask [256*131072] f32 (0/1).
#define ROWS 256
#define COLS 131072
#define SHARP 10.0f

typedef float vf4 __attribute__((ext_vector_type(4)));
typedef float vf2 __attribute__((ext_vector_type(2)));

// Structure = round-2 (best verified, 352.2 us): each WAVE owns 1024 contiguous
// elements of one row; lane l, chunk c handles [wbase + c*256 + 4l, +4). Every
// vector load/store is 64 lanes x 16B = 1KB contiguous (full lines; nt stores
// can't amplify — round-1 lesson). Round-4 lesson: shfl halos are SLOWER than
// loads (lgkmcnt dependency stalls), so halos come from memory — but paired:
//
// Round-5 change (data movement only; every consumed value bit-identical to
// round 2): the two left halos x[col-2],x[col-1] are consecutive and (col-2)*4
// is 8B-aligned (col % 4 == 0), so ONE global_load_dwordx2 replaces two scalar
// loads; same for the right pair at col+4. 5 -> 3 loads per chunk
// (28 -> 20 VMEM instrs/thread). Edge handling: clamp load address to stay
// in-row + 2 cndmasks, only live on the row-boundary lanes.
// Math untouched (expf + IEEE div, same fmax chain shape): the s >= thresh
// mask boundary is a correctness cliff — no fast-math, no reassociation.
__global__ __launch_bounds__(256) void peak_extract_kernel(
    const float* __restrict__ x,
    const float* __restrict__ logit_thresh,
    float* __restrict__ smooth,
    float* __restrict__ mask)
{
    const float thresh = 1.0f / (1.0f + expf(-logit_thresh[0]));

    const long long gid = (long long)blockIdx.x * blockDim.x + threadIdx.x;
    const int wave = (int)(gid >> 6);
    const int lane = (int)(gid & 63);
    const long long wbase = (long long)wave << 10;   // 1024 elements per wave
    const int row  = (int)(wbase >> 17);             // COLS = 2^17
    const int col0 = (((int)wbase) & (COLS - 1)) + (lane << 2);

    const float* __restrict__ xr = x + (long long)row * COLS;

    // All loads issued upfront: per chunk 1x dwordx4 + 2x dwordx2, all
    // independent -> 12 lines in flight per thread before any compute.
    vf4 a[4];
    vf2 L[4], R[4];
#pragma unroll
    for (int c = 0; c < 4; ++c) {
        const int col = col0 + (c << 8);             // +256 elements per chunk
        a[c] = *(const vf4*)(xr + col);
        // (col-2)*4 and (col+4)*4 are 8B-aligned; clamp keeps them in-row.
        const int lcol = (c == 0) ? max(col - 2, 0)        : (col - 2);
        const int rcol = (c == 3) ? min(col + 4, COLS - 2) : (col + 4);
        L[c] = *(const vf2*)(xr + lcol);
        R[c] = *(const vf2*)(xr + rcol);
    }

    const long long rbase = (long long)row * COLS;

#pragma unroll
    for (int c = 0; c < 4; ++c) {
        const int col = col0 + (c << 8);
        // Edge fixes (values identical to round 2's clamped scalar loads):
        // col==0:      L was loaded at 0 -> {x0,x1}; ref wants v0=x0, v1=x0.
        // col==COLS-4: R was loaded at COLS-2 -> {x[C-2],x[C-1]};
        //              ref wants v6=x[C-1], v7=x[C-1].
        const bool eL = (c == 0) && (col == 0);
        const bool eR = (c == 3) && (col == COLS - 4);

        float v[8];
        v[0] = L[c][0];
        v[1] = eL ? L[c][0] : L[c][1];
        v[2] = a[c][0]; v[3] = a[c][1]; v[4] = a[c][2]; v[5] = a[c][3];
        v[6] = eR ? R[c][1] : R[c][0];
        v[7] = R[c][1];

        vf4 sv, mv;
#pragma unroll
        for (int k = 0; k < 4; ++k) {
            // pooled = max over window of 5 centered at element k (v[k..k+4]) —
            // same chain shape as the passing round-0/2/4 kernels.
            float p = v[k];
            p = fmaxf(p, v[k + 1]);
            p = fmaxf(p, v[k + 2]);
            p = fmaxf(p, v[k + 3]);
            p = fmaxf(p, v[k + 4]);
            const float xv   = v[k + 2];
            const float gate = 1.0f / (1.0f + expf(-SHARP * (xv - thresh)));
            const float lm   = 1.0f / (1.0f + expf(-SHARP * (xv - p)));
            const float s    = xv * gate * lm;
            sv[k] = s;
            mv[k] = (s >= thresh) ? 1.0f : 0.0f;
        }
        __builtin_nontemporal_store(sv, (vf4*)(smooth + rbase + col));
        __builtin_nontemporal_store(mv, (vf4*)(mask   + rbase + col));
    }
}

extern "C" void kernel_launch(void* const* d_in, const int* in_sizes, int n_in,
                              void* d_out, int out_size, void* d_ws, size_t ws_size,
                              hipStream_t stream) {
    const float* x            = (const float*)d_in[0];
    const float* logit_thresh = (const float*)d_in[1];

    float* smooth = (float*)d_out;                          // first output, ROWS*COLS f32
    float* mask   = (float*)d_out + (long long)ROWS * COLS; // second output, ROWS*COLS f32

    const long long n_elem   = (long long)ROWS * COLS;      // 33,554,432
    const long long n_thread = n_elem / 16;                 // 2,097,152
    const int block = 256;
    const int grid  = (int)(n_thread / block);              // 8,192

    peak_extract_kernel<<<grid, block, 0, stream>>>(x, logit_thresh, smooth, mask);
}